// Round 5
// baseline (722.102 us; speedup 1.0000x reference)
//
#include <hip/hip_runtime.h>

#define DIM 512
#define HID 2048
#define NE 8

typedef _Float16 half8v __attribute__((ext_vector_type(8)));
typedef _Float16 half4v __attribute__((ext_vector_type(4)));
typedef float f32x4 __attribute__((ext_vector_type(4)));

__device__ __forceinline__ void gload16(const void* g, void* l) {
  __builtin_amdgcn_global_load_lds(
      (const __attribute__((address_space(1))) void*)g,
      (__attribute__((address_space(3))) void*)l, 16, 0, 0);
}

// ---------------- transpose + cast: z=0..8 (8 experts + master) ----------------
// src fp32 [R][C] -> dst fp16 [z][C][R]
__global__ void k_transpose_cast9(const float* __restrict__ src_e,
                                  const float* __restrict__ src_m,
                                  _Float16* __restrict__ dst, int R, int C) {
  __shared__ _Float16 ts[64][66];
  int z = blockIdx.z;
  const float* src = (z == NE) ? src_m : src_e + (size_t)z * R * C;
  _Float16* d = dst + (size_t)z * R * C;
  int c0 = blockIdx.x * 64, r0 = blockIdx.y * 64;
  int t = threadIdx.x;
  int rr = t >> 4, cc = (t & 15) * 4;
  #pragma unroll
  for (int i = 0; i < 4; i++) {
    int row = rr + i * 16;
    float4 v = *(const float4*)&src[(size_t)(r0 + row) * C + c0 + cc];
    ts[row][cc + 0] = (_Float16)v.x; ts[row][cc + 1] = (_Float16)v.y;
    ts[row][cc + 2] = (_Float16)v.z; ts[row][cc + 3] = (_Float16)v.w;
  }
  __syncthreads();
  int cr = t >> 4, rb = (t & 15) * 4;
  #pragma unroll
  for (int i = 0; i < 4; i++) {
    int c = cr + i * 16;
    half4v o = { ts[rb + 0][c], ts[rb + 1][c], ts[rb + 2][c], ts[rb + 3][c] };
    *(half4v*)&d[(size_t)(c0 + c) * R + r0 + rb] = o;
  }
}

// ---------------- router (+ fused fp32->fp16 cast of x) ----------------
#define RT_TOK 16
__global__ void k_router(const float* __restrict__ x, const float* __restrict__ gw,
                         _Float16* __restrict__ xb,
                         int* __restrict__ counts, int* __restrict__ perm,
                         float* __restrict__ pgate, int T) {
  __shared__ float xs[RT_TOK][520];
  __shared__ float gwt[8][520];
  __shared__ float lg[RT_TOK][8];
  int t = threadIdx.x;                 // 128 threads
  int tk0 = blockIdx.x * RT_TOK;
  for (int i = t; i < DIM * NE; i += 128) {
    int k = i >> 3, e = i & 7;
    gwt[e][k] = gw[i];
  }
  for (int i = t; i < RT_TOK * (DIM / 4); i += 128) {
    int row = i >> 7; int c4 = i & 127;       // DIM/4 == 128
    float4 v = *(const float4*)&x[(size_t)(tk0 + row) * DIM + c4 * 4];
    xs[row][c4 * 4 + 0] = v.x; xs[row][c4 * 4 + 1] = v.y;
    xs[row][c4 * 4 + 2] = v.z; xs[row][c4 * 4 + 3] = v.w;
    half4v h = { (_Float16)v.x, (_Float16)v.y, (_Float16)v.z, (_Float16)v.w };
    *(half4v*)&xb[(size_t)(tk0 + row) * DIM + c4 * 4] = h;
  }
  __syncthreads();
  int tok = t >> 3, e = t & 7;
  float acc = 0.f;
  for (int k = 0; k < DIM; k += 4) {
    float4 xv = *(const float4*)&xs[tok][k];
    float4 wv = *(const float4*)&gwt[e][k];
    acc += xv.x * wv.x + xv.y * wv.y + xv.z * wv.z + xv.w * wv.w;
  }
  lg[tok][e] = acc;
  __syncthreads();
  if (t < RT_TOK) {
    float v0 = -1e30f, v1 = -1e30f; int i0 = 0, i1 = 0;
    #pragma unroll
    for (int j = 0; j < 8; j++) { float v = lg[t][j]; if (v > v0) { v0 = v; i0 = j; } }
    #pragma unroll
    for (int j = 0; j < 8; j++) { if (j == i0) continue; float v = lg[t][j]; if (v > v1) { v1 = v; i1 = j; } }
    float g0 = 1.f / (1.f + __expf(v1 - v0));
    float g1 = 1.f - g0;
    int token = tk0 + t;
    int p0 = atomicAdd(&counts[i0], 1);
    perm[i0 * T + p0] = token; pgate[i0 * T + p0] = g0;
    int p1 = atomicAdd(&counts[i1], 1);
    perm[i1 * T + p1] = token; pgate[i1 * T + p1] = g1;
  }
}

// ---------------- MFMA GEMM: 256x128 tile, BK=32, 8 waves (512 thr) ----------------
// Triple-buffered depth-2 pipeline: per iter
//   vmcnt(3) -> barrier -> STAGE(kt+2) -> setprio(1) MFMA(kt) setprio(0)
// Stage = 24KB: A 256x32 fp16 (16KB) + B 128x32 fp16 (8KB). 3 stages = 72KB LDS.
// Chunk-XOR swizzle (global-source side + read side, same involution).
// z = 0..8; e==8 is the master (identity perm, gate=1, hbase=2T).
// MODE 0: fc1 -> gelu -> h (fp16).  MODE 2: fc2 -> gated atomicAdd into zeroed out.

#define STG 24576           // bytes per stage
#define BOFF 16384          // B region offset within a stage

__device__ __forceinline__ void compute_tile(const char* base,
                                             int wm, int wn, int rb,
                                             f32x4 acc[4][4]) {
  const char* ab = base;
  const char* bb = base + BOFF;
  half8v af[4], bf[4];
  #pragma unroll
  for (int mi = 0; mi < 4; mi++)
    af[mi] = *(const half8v*)(ab + ((wm + mi * 16) << 6) + rb);
  #pragma unroll
  for (int ni = 0; ni < 4; ni++)
    bf[ni] = *(const half8v*)(bb + ((wn + ni * 16) << 6) + rb);
  #pragma unroll
  for (int mi = 0; mi < 4; mi++)
    #pragma unroll
    for (int ni = 0; ni < 4; ni++)
      acc[mi][ni] = __builtin_amdgcn_mfma_f32_16x16x32_f16(af[mi], bf[ni], acc[mi][ni], 0, 0, 0);
}

template<int K, int MODE>
__global__ __launch_bounds__(512) void k_gemm(
    const _Float16* __restrict__ A,    // rows of length K (MODE0: xb, MODE2: hbuf)
    const _Float16* __restrict__ Bt,   // [9][N][K] fp16 (pre-transposed, slot 8 = master)
    const float* __restrict__ ebias,   // expert bias [8][N]
    const float* __restrict__ mbias,   // master bias [N]
    const int* __restrict__ counts,    // [8]
    const int* __restrict__ perm,      // [8][T]
    const float* __restrict__ pgate,   // [8][T]
    _Float16* __restrict__ hout,       // MODE0 dest [3T, HID]
    float* __restrict__ out,           // MODE2 dest [T, DIM] (pre-zeroed)
    int T) {
  constexpr int N = (MODE == 0) ? HID : DIM;
  constexpr int KT = K / 32;
  int e = blockIdx.z;
  bool isM = (e == NE);
  int count = isM ? T : counts[e];
  int m0 = blockIdx.x * 256;
  if (m0 >= count) return;
  int n0 = blockIdx.y * 128;
  // inline prefix-sum for h-row base (master block at [2T,3T))
  int hbase = 0;
  if (isM) hbase = 2 * T;
  else for (int i = 0; i < e; i++) hbase += counts[i];
  const _Float16* Be = Bt + (size_t)e * N * K;
  const float* be = isM ? mbias : ebias + (size_t)e * N;

  __shared__ _Float16 S[3 * STG / 2];

  int t = threadIdx.x;                 // 512 threads, 8 waves
  int lane = t & 63;
  int wid = t >> 6;
  int wm = (wid & 3) * 64, wn = (wid >> 2) * 64;   // 4m x 2n wave grid

  // Staging: A chunks ca = t, t+512 (row=ca>>2 in [0,256), c=ca&3);
  //          B chunk  cb = t        (row in [0,128)).
  // Source swizzle: cg = c ^ ((row + (row>>2)) & 3).
  const char* aSrc0; const char* aSrc1; const char* bSrc0;
  {
    int r0a = t >> 2,        cg0 = (t & 3) ^ ((r0a + (r0a >> 2)) & 3);
    int r1a = r0a + 128,     cg1 = (t & 3) ^ ((r1a + (r1a >> 2)) & 3);
    int pos0 = m0 + r0a; int pr0 = pos0 < count ? pos0 : count - 1;
    int pos1 = m0 + r1a; int pr1 = pos1 < count ? pos1 : count - 1;
    int arow0, arow1;
    if (MODE == 0) {
      arow0 = isM ? pr0 : perm[e * T + pr0];
      arow1 = isM ? pr1 : perm[e * T + pr1];
    } else {
      arow0 = hbase + pr0; arow1 = hbase + pr1;
    }
    aSrc0 = (const char*)(A + (size_t)arow0 * K) + cg0 * 16;
    aSrc1 = (const char*)(A + (size_t)arow1 * K) + cg1 * 16;
    bSrc0 = (const char*)(Be + (size_t)(n0 + r0a) * K) + cg0 * 16;
  }

  // Read-side swizzled chunk (per-lane constant):
  // row&3 = lane&3, (row>>2)&3 = (lane>>2)&3  -> qa = q ^ ((lane&3)+((lane>>2)&3) & 3)
  int qa = (lane >> 4) ^ (((lane & 3) + ((lane >> 2) & 3)) & 3);
  int rb = ((lane & 15) << 6) + (qa << 4);

  f32x4 acc[4][4] = {};

  char* p0 = (char*)S;
  char* p1 = (char*)S + STG;
  char* p2 = (char*)S + 2 * STG;

#define STAGE_TO(base, off) do { \
    gload16(aSrc0 + (off), (base) + t * 16); \
    gload16(aSrc1 + (off), (base) + t * 16 + 8192); \
    gload16(bSrc0 + (off), (base) + BOFF + t * 16); \
  } while (0)

  // prologue: tiles 0,1 in flight (3 loads each)
  STAGE_TO(p0, 0);
  STAGE_TO(p1, 64);

  for (int kt = 0; kt < KT; ++kt) {
    if (kt + 1 < KT) { asm volatile("s_waitcnt vmcnt(3)" ::: "memory"); }
    else             { asm volatile("s_waitcnt vmcnt(0)" ::: "memory"); }
    __builtin_amdgcn_s_barrier();
    if (kt + 2 < KT) STAGE_TO(p2, (kt + 2) * 64);
    __builtin_amdgcn_s_setprio(1);
    compute_tile(p0, wm, wn, rb, acc);
    __builtin_amdgcn_s_setprio(0);
    char* tp = p0; p0 = p1; p1 = p2; p2 = tp;
  }
#undef STAGE_TO

  int cl = lane & 15, rh = (lane >> 4) * 4;
  float bv[4];
  #pragma unroll
  for (int ni = 0; ni < 4; ni++) bv[ni] = be[n0 + wn + ni * 16 + cl];
  #pragma unroll
  for (int mi = 0; mi < 4; mi++) {
    #pragma unroll
    for (int r = 0; r < 4; r++) {
      int pos = m0 + wm + mi * 16 + rh + r;
      if (pos >= count) continue;
      int orow; float g = 1.f;
      if (MODE == 0) orow = hbase + pos;
      else {
        orow = isM ? pos : perm[e * T + pos];
        if (!isM) g = pgate[e * T + pos];
      }
      #pragma unroll
      for (int ni = 0; ni < 4; ni++) {
        float v = acc[mi][ni][r] + bv[ni];
        int col = n0 + wn + ni * 16 + cl;
        if (MODE == 0) {
          // jax.nn.gelu approximate=True: x*sigmoid(2*sqrt(2/pi)*(x+0.044715x^3))
          float ge = v / (1.f + __expf(-1.5957691216057308f * (v + 0.044715f * v * v * v)));
          hout[(size_t)orow * HID + col] = (_Float16)ge;
        } else {
          unsafeAtomicAdd(&out[(size_t)orow * DIM + col], g * v);
        }
      }
    }
  }
}

extern "C" void kernel_launch(void* const* d_in, const int* in_sizes, int n_in,
                              void* d_out, int out_size, void* d_ws, size_t ws_size,
                              hipStream_t stream) {
  const float* x         = (const float*)d_in[0];
  const float* gate_w    = (const float*)d_in[1];
  const float* master_w1 = (const float*)d_in[2];
  const float* master_b1 = (const float*)d_in[3];
  const float* master_w2 = (const float*)d_in[4];
  const float* master_b2 = (const float*)d_in[5];
  const float* expert_w1 = (const float*)d_in[6];
  const float* expert_b1 = (const float*)d_in[7];
  const float* expert_w2 = (const float*)d_in[8];
  const float* expert_b2 = (const float*)d_in[9];
  float* out = (float*)d_out;
  int T = in_sizes[0] / DIM;   // 16384 tokens

  // ---- workspace layout (~295 MB) ----
  char* p = (char*)d_ws;
  _Float16* xb   = (_Float16*)p; p += (size_t)T * DIM * 2;
  _Float16* wb1t = (_Float16*)p; p += (size_t)9 * HID * DIM * 2;  // [e][HID][DIM], master=8
  _Float16* wb2t = (_Float16*)p; p += (size_t)9 * DIM * HID * 2;  // [e][DIM][HID], master=8
  int*   counts  = (int*)p;      p += 256;
  int*   perm    = (int*)p;      p += (size_t)8 * T * 4;
  float* pgate   = (float*)p;    p += (size_t)8 * T * 4;
  _Float16* hbuf = (_Float16*)p; p += (size_t)3 * T * HID * 2;    // experts [0,2T), master [2T,3T)

  hipMemsetAsync(counts, 0, 64, stream);
  hipMemsetAsync(out, 0, (size_t)T * DIM * 4, stream);   // fc2 accumulates via atomics

  k_router<<<T / RT_TOK, 128, 0, stream>>>(x, gate_w, xb, counts, perm, pgate, T);

  k_transpose_cast9<<<dim3(HID / 64, DIM / 64, 9), 256, 0, stream>>>(
      expert_w1, master_w1, wb1t, DIM, HID);
  k_transpose_cast9<<<dim3(DIM / 64, HID / 64, 9), 256, 0, stream>>>(
      expert_w2, master_w2, wb2t, HID, DIM);

  // fc1 for all 9 (8 experts + master): x @ w1 -> gelu -> hbuf
  k_gemm<DIM, 0><<<dim3(T / 256, HID / 128, 9), 512, 0, stream>>>(
      xb, wb1t, expert_b1, master_b1, counts, perm, nullptr,
      hbuf, nullptr, T);
  // fc2 for all 9: hbuf @ w2 -> gated atomicAdd into out
  k_gemm<HID, 2><<<dim3(T / 256, DIM / 128, 9), 512, 0, stream>>>(
      hbuf, wb2t, expert_b2, master_b2, counts, perm, pgate,
      nullptr, out, T);
}

// Round 6
// 717.308 us; speedup vs baseline: 1.0067x; 1.0067x over previous
//
#include <hip/hip_runtime.h>

#define DIM 512
#define HID 2048
#define NE 8

typedef _Float16 half8v __attribute__((ext_vector_type(8)));
typedef _Float16 half4v __attribute__((ext_vector_type(4)));
typedef float f32x4 __attribute__((ext_vector_type(4)));

__device__ __forceinline__ void gload16(const void* g, void* l) {
  __builtin_amdgcn_global_load_lds(
      (const __attribute__((address_space(1))) void*)g,
      (__attribute__((address_space(3))) void*)l, 16, 0, 0);
}

// ---------------- transpose + cast: z=0..8 (8 experts + master) ----------------
// src fp32 [R][C] -> dst fp16 [z][C][R]
__global__ void k_transpose_cast9(const float* __restrict__ src_e,
                                  const float* __restrict__ src_m,
                                  _Float16* __restrict__ dst, int R, int C) {
  __shared__ _Float16 ts[64][66];
  int z = blockIdx.z;
  const float* src = (z == NE) ? src_m : src_e + (size_t)z * R * C;
  _Float16* d = dst + (size_t)z * R * C;
  int c0 = blockIdx.x * 64, r0 = blockIdx.y * 64;
  int t = threadIdx.x;
  int rr = t >> 4, cc = (t & 15) * 4;
  #pragma unroll
  for (int i = 0; i < 4; i++) {
    int row = rr + i * 16;
    float4 v = *(const float4*)&src[(size_t)(r0 + row) * C + c0 + cc];
    ts[row][cc + 0] = (_Float16)v.x; ts[row][cc + 1] = (_Float16)v.y;
    ts[row][cc + 2] = (_Float16)v.z; ts[row][cc + 3] = (_Float16)v.w;
  }
  __syncthreads();
  int cr = t >> 4, rb = (t & 15) * 4;
  #pragma unroll
  for (int i = 0; i < 4; i++) {
    int c = cr + i * 16;
    half4v o = { ts[rb + 0][c], ts[rb + 1][c], ts[rb + 2][c], ts[rb + 3][c] };
    *(half4v*)&d[(size_t)(c0 + c) * R + r0 + rb] = o;
  }
}

// ---------------- router (+ fused fp32->fp16 cast of x) ----------------
#define RT_TOK 16
__global__ void k_router(const float* __restrict__ x, const float* __restrict__ gw,
                         _Float16* __restrict__ xb,
                         int* __restrict__ counts, int* __restrict__ perm,
                         float* __restrict__ pgate, int T) {
  __shared__ float xs[RT_TOK][520];
  __shared__ float gwt[8][520];
  __shared__ float lg[RT_TOK][8];
  int t = threadIdx.x;                 // 128 threads
  int tk0 = blockIdx.x * RT_TOK;
  for (int i = t; i < DIM * NE; i += 128) {
    int k = i >> 3, e = i & 7;
    gwt[e][k] = gw[i];
  }
  for (int i = t; i < RT_TOK * (DIM / 4); i += 128) {
    int row = i >> 7; int c4 = i & 127;       // DIM/4 == 128
    float4 v = *(const float4*)&x[(size_t)(tk0 + row) * DIM + c4 * 4];
    xs[row][c4 * 4 + 0] = v.x; xs[row][c4 * 4 + 1] = v.y;
    xs[row][c4 * 4 + 2] = v.z; xs[row][c4 * 4 + 3] = v.w;
    half4v h = { (_Float16)v.x, (_Float16)v.y, (_Float16)v.z, (_Float16)v.w };
    *(half4v*)&xb[(size_t)(tk0 + row) * DIM + c4 * 4] = h;
  }
  __syncthreads();
  int tok = t >> 3, e = t & 7;
  float acc = 0.f;
  for (int k = 0; k < DIM; k += 4) {
    float4 xv = *(const float4*)&xs[tok][k];
    float4 wv = *(const float4*)&gwt[e][k];
    acc += xv.x * wv.x + xv.y * wv.y + xv.z * wv.z + xv.w * wv.w;
  }
  lg[tok][e] = acc;
  __syncthreads();
  if (t < RT_TOK) {
    float v0 = -1e30f, v1 = -1e30f; int i0 = 0, i1 = 0;
    #pragma unroll
    for (int j = 0; j < 8; j++) { float v = lg[t][j]; if (v > v0) { v0 = v; i0 = j; } }
    #pragma unroll
    for (int j = 0; j < 8; j++) { if (j == i0) continue; float v = lg[t][j]; if (v > v1) { v1 = v; i1 = j; } }
    float g0 = 1.f / (1.f + __expf(v1 - v0));
    float g1 = 1.f - g0;
    int token = tk0 + t;
    int p0 = atomicAdd(&counts[i0], 1);
    perm[i0 * T + p0] = token; pgate[i0 * T + p0] = g0;
    int p1 = atomicAdd(&counts[i1], 1);
    perm[i1 * T + p1] = token; pgate[i1 * T + p1] = g1;
  }
}

// ---------------- MFMA GEMM: 256x256 tile, BK=64, 8 waves (512 thr) ----------------
// Double-buffered (128KB dynamic LDS), depth-1 counted prefetch:
//   bar -> STAGE(kt+1) -> vmcnt(8) -> bar -> setprio(1) 64xMFMA setprio(0)
// LDS rows are 128B (64 fp16, 8x16B chunks). Row-XOR swizzle (rule #21):
//   LDS slot (row, c) holds logical chunk c ^ (row&7); staged by inverse-
//   swizzling the GLOBAL source chunk (linear gload_lds dest), read with the
//   same XOR. Residual conflict: 2-way (free).
// z = 0..8; e==8 is the master (identity perm, gate=1, hbase=2T).
// MODE 0: fc1 -> gelu -> h (fp16).  MODE 2: fc2 -> gated atomicAdd into zeroed out.

template<int K, int MODE>
__global__ __launch_bounds__(512, 1) void k_gemm(
    const _Float16* __restrict__ A,    // rows of length K (MODE0: xb, MODE2: hbuf)
    const _Float16* __restrict__ Bt,   // [9][N][K] fp16 (pre-transposed, slot 8 = master)
    const float* __restrict__ ebias,   // expert bias [8][N]
    const float* __restrict__ mbias,   // master bias [N]
    const int* __restrict__ counts,    // [8]
    const int* __restrict__ perm,      // [8][T]
    const float* __restrict__ pgate,   // [8][T]
    _Float16* __restrict__ hout,       // MODE0 dest [3T, HID]
    float* __restrict__ out,           // MODE2 dest [T, DIM] (pre-zeroed)
    int T) {
  constexpr int N = (MODE == 0) ? HID : DIM;
  constexpr int KT = K / 64;
  extern __shared__ char S[];          // 131072 bytes: 2 x (A 32KB + B 32KB)
  int e = blockIdx.z;
  bool isM = (e == NE);
  int count = isM ? T : counts[e];
  int m0 = blockIdx.x * 256;
  if (m0 >= count) return;
  int n0 = blockIdx.y * 256;
  int hbase = 0;
  if (isM) hbase = 2 * T;
  else for (int i = 0; i < e; i++) hbase += counts[i];
  const _Float16* Be = Bt + (size_t)e * N * K;
  const float* be = isM ? mbias : ebias + (size_t)e * N;

  int t = threadIdx.x;                 // 512 threads, 8 waves (2M x 4N)
  int lane = t & 63;
  int wid = t >> 6;
  int wm = (wid >> 2) * 128;           // wave row base (0 or 128)
  int wn = (wid & 3) * 64;             // wave col base (0,64,128,192)

  // ---- staging sources (linear LDS dest; inverse-swizzled global chunk) ----
  // thread t, region j: LDS offset j*8192 + t*16  ->  row j*64 + (t>>3), chunk t&7.
  // source global chunk = (t&7) ^ (row&7) = (t&7) ^ ((t>>3)&7)   (j*64 == 0 mod 8)
  int srow = t >> 3;
  int schunk = (t & 7) ^ (srow & 7);
  const char *aP0, *aP1, *aP2, *aP3, *bP0, *bP1, *bP2, *bP3;
  {
    int r0 = srow, r1 = 64 + srow, r2 = 128 + srow, r3 = 192 + srow;
    int p0 = m0 + r0; p0 = p0 < count ? p0 : count - 1;
    int p1 = m0 + r1; p1 = p1 < count ? p1 : count - 1;
    int p2 = m0 + r2; p2 = p2 < count ? p2 : count - 1;
    int p3 = m0 + r3; p3 = p3 < count ? p3 : count - 1;
    int a0, a1, a2, a3;
    if (MODE == 0) {
      a0 = isM ? p0 : perm[e * T + p0];
      a1 = isM ? p1 : perm[e * T + p1];
      a2 = isM ? p2 : perm[e * T + p2];
      a3 = isM ? p3 : perm[e * T + p3];
    } else {
      a0 = hbase + p0; a1 = hbase + p1; a2 = hbase + p2; a3 = hbase + p3;
    }
    aP0 = (const char*)(A + (size_t)a0 * K) + schunk * 16;
    aP1 = (const char*)(A + (size_t)a1 * K) + schunk * 16;
    aP2 = (const char*)(A + (size_t)a2 * K) + schunk * 16;
    aP3 = (const char*)(A + (size_t)a3 * K) + schunk * 16;
    bP0 = (const char*)(Be + (size_t)(n0 + r0) * K) + schunk * 16;
    bP1 = (const char*)(Be + (size_t)(n0 + r1) * K) + schunk * 16;
    bP2 = (const char*)(Be + (size_t)(n0 + r2) * K) + schunk * 16;
    bP3 = (const char*)(Be + (size_t)(n0 + r3) * K) + schunk * 16;
  }

  // ---- read-side swizzled byte offsets (per-lane constant) ----
  // row = (frag base) + (lane&15): row&7 == lane&7. logical chunk q = kk*4 + (lane>>4).
  int l15 = lane & 15, l4 = lane >> 4, l7 = lane & 7;
  int roff0 = l15 * 128 + ((l4 ^ l7) << 4);          // kk=0
  int roff1 = l15 * 128 + (((4 + l4) ^ l7) << 4);    // kk=1

  f32x4 acc[8][4] = {};

  char* buf0 = S;
  char* buf1 = S + 65536;

#define STAGE(base, ktile) do { \
    const int off_ = (ktile) * 128; \
    gload16(aP0 + off_, (base) + t * 16); \
    gload16(aP1 + off_, (base) + 8192 + t * 16); \
    gload16(aP2 + off_, (base) + 16384 + t * 16); \
    gload16(aP3 + off_, (base) + 24576 + t * 16); \
    gload16(bP0 + off_, (base) + 32768 + t * 16); \
    gload16(bP1 + off_, (base) + 40960 + t * 16); \
    gload16(bP2 + off_, (base) + 49152 + t * 16); \
    gload16(bP3 + off_, (base) + 57344 + t * 16); \
  } while (0)

  STAGE(buf0, 0);
  for (int kt = 0; kt < KT; ++kt) {
    __builtin_amdgcn_s_barrier();      // all waves done reading the buf we stage into
    if (kt + 1 < KT) {
      STAGE((kt & 1) ? buf0 : buf1, kt + 1);
      asm volatile("s_waitcnt vmcnt(8)" ::: "memory");   // kt's 8 loads landed
    } else {
      asm volatile("s_waitcnt vmcnt(0)" ::: "memory");
    }
    __builtin_amdgcn_sched_barrier(0);
    __builtin_amdgcn_s_barrier();      // everyone's loads landed
    const char* base = (kt & 1) ? buf1 : buf0;
    const char* ab = base;
    const char* bb = base + 32768;
    __builtin_amdgcn_s_setprio(1);
    #pragma unroll
    for (int kk = 0; kk < 2; ++kk) {
      int ro = kk ? roff1 : roff0;
      half8v af[8], bf[4];
      #pragma unroll
      for (int mi = 0; mi < 8; mi++)
        af[mi] = *(const half8v*)(ab + (wm + mi * 16) * 128 + ro);
      #pragma unroll
      for (int ni = 0; ni < 4; ni++)
        bf[ni] = *(const half8v*)(bb + (wn + ni * 16) * 128 + ro);
      #pragma unroll
      for (int mi = 0; mi < 8; mi++)
        #pragma unroll
        for (int ni = 0; ni < 4; ni++)
          acc[mi][ni] = __builtin_amdgcn_mfma_f32_16x16x32_f16(af[mi], bf[ni], acc[mi][ni], 0, 0, 0);
    }
    __builtin_amdgcn_s_setprio(0);
  }
#undef STAGE

  // ---- epilogue ----
  int cl = l15, rh = l4 * 4;
  float bv[4];
  #pragma unroll
  for (int ni = 0; ni < 4; ni++) bv[ni] = be[n0 + wn + ni * 16 + cl];
  #pragma unroll
  for (int mi = 0; mi < 8; mi++) {
    #pragma unroll
    for (int r = 0; r < 4; r++) {
      int pos = m0 + wm + mi * 16 + rh + r;
      if (pos >= count) continue;
      int orow; float g = 1.f;
      if (MODE == 0) orow = hbase + pos;
      else {
        orow = isM ? pos : perm[e * T + pos];
        if (!isM) g = pgate[e * T + pos];
      }
      #pragma unroll
      for (int ni = 0; ni < 4; ni++) {
        float v = acc[mi][ni][r] + bv[ni];
        int col = n0 + wn + ni * 16 + cl;
        if (MODE == 0) {
          // jax.nn.gelu approximate=True: x*sigmoid(2*sqrt(2/pi)*(x+0.044715x^3))
          float ge = v / (1.f + __expf(-1.5957691216057308f * (v + 0.044715f * v * v * v)));
          hout[(size_t)orow * HID + col] = (_Float16)ge;
        } else {
          unsafeAtomicAdd(&out[(size_t)orow * DIM + col], g * v);
        }
      }
    }
  }
}

extern "C" void kernel_launch(void* const* d_in, const int* in_sizes, int n_in,
                              void* d_out, int out_size, void* d_ws, size_t ws_size,
                              hipStream_t stream) {
  const float* x         = (const float*)d_in[0];
  const float* gate_w    = (const float*)d_in[1];
  const float* master_w1 = (const float*)d_in[2];
  const float* master_b1 = (const float*)d_in[3];
  const float* master_w2 = (const float*)d_in[4];
  const float* master_b2 = (const float*)d_in[5];
  const float* expert_w1 = (const float*)d_in[6];
  const float* expert_b1 = (const float*)d_in[7];
  const float* expert_w2 = (const float*)d_in[8];
  const float* expert_b2 = (const float*)d_in[9];
  float* out = (float*)d_out;
  int T = in_sizes[0] / DIM;   // 16384 tokens

  // ---- workspace layout (~295 MB) ----
  char* p = (char*)d_ws;
  _Float16* xb   = (_Float16*)p; p += (size_t)T * DIM * 2;
  _Float16* wb1t = (_Float16*)p; p += (size_t)9 * HID * DIM * 2;  // [e][HID][DIM], master=8
  _Float16* wb2t = (_Float16*)p; p += (size_t)9 * DIM * HID * 2;  // [e][DIM][HID], master=8
  int*   counts  = (int*)p;      p += 256;
  int*   perm    = (int*)p;      p += (size_t)8 * T * 4;
  float* pgate   = (float*)p;    p += (size_t)8 * T * 4;
  _Float16* hbuf = (_Float16*)p; p += (size_t)3 * T * HID * 2;    // experts [0,2T), master [2T,3T)

  // allow 128KB dynamic LDS for the GEMMs (idempotent; not stream-ordered)
  (void)hipFuncSetAttribute((const void*)&k_gemm<DIM, 0>,
                            hipFuncAttributeMaxDynamicSharedMemorySize, 131072);
  (void)hipFuncSetAttribute((const void*)&k_gemm<HID, 2>,
                            hipFuncAttributeMaxDynamicSharedMemorySize, 131072);

  hipMemsetAsync(counts, 0, 64, stream);
  hipMemsetAsync(out, 0, (size_t)T * DIM * 4, stream);   // fc2 accumulates via atomics

  k_router<<<T / RT_TOK, 128, 0, stream>>>(x, gate_w, xb, counts, perm, pgate, T);

  k_transpose_cast9<<<dim3(HID / 64, DIM / 64, 9), 256, 0, stream>>>(
      expert_w1, master_w1, wb1t, DIM, HID);
  k_transpose_cast9<<<dim3(DIM / 64, HID / 64, 9), 256, 0, stream>>>(
      expert_w2, master_w2, wb2t, HID, DIM);

  // fc1 for all 9 (8 experts + master): x @ w1 -> gelu -> hbuf
  k_gemm<DIM, 0><<<dim3(T / 256, HID / 256, 9), 512, 131072, stream>>>(
      xb, wb1t, expert_b1, master_b1, counts, perm, nullptr,
      hbuf, nullptr, T);
  // fc2 for all 9: hbuf @ w2 -> gated atomicAdd into out
  k_gemm<HID, 2><<<dim3(T / 256, DIM / 256, 9), 512, 131072, stream>>>(
      hbuf, wb2t, expert_b2, master_b2, counts, perm, pgate,
      nullptr, out, T);
}

// Round 7
// 609.762 us; speedup vs baseline: 1.1842x; 1.1764x over previous
//
#include <hip/hip_runtime.h>

#define DIM 512
#define HID 2048
#define NE 8

typedef _Float16 half8v __attribute__((ext_vector_type(8)));
typedef _Float16 half4v __attribute__((ext_vector_type(4)));
typedef float f32x4 __attribute__((ext_vector_type(4)));

__device__ __forceinline__ void gload16(const void* g, void* l) {
  __builtin_amdgcn_global_load_lds(
      (const __attribute__((address_space(1))) void*)g,
      (__attribute__((address_space(3))) void*)l, 16, 0, 0);
}

// ---------------- transpose + cast: z=0..8 (8 experts + master) ----------------
// src fp32 [R][C] -> dst fp16 [z][C][R]
__global__ void k_transpose_cast9(const float* __restrict__ src_e,
                                  const float* __restrict__ src_m,
                                  _Float16* __restrict__ dst, int R, int C) {
  __shared__ _Float16 ts[64][66];
  int z = blockIdx.z;
  const float* src = (z == NE) ? src_m : src_e + (size_t)z * R * C;
  _Float16* d = dst + (size_t)z * R * C;
  int c0 = blockIdx.x * 64, r0 = blockIdx.y * 64;
  int t = threadIdx.x;
  int rr = t >> 4, cc = (t & 15) * 4;
  #pragma unroll
  for (int i = 0; i < 4; i++) {
    int row = rr + i * 16;
    float4 v = *(const float4*)&src[(size_t)(r0 + row) * C + c0 + cc];
    ts[row][cc + 0] = (_Float16)v.x; ts[row][cc + 1] = (_Float16)v.y;
    ts[row][cc + 2] = (_Float16)v.z; ts[row][cc + 3] = (_Float16)v.w;
  }
  __syncthreads();
  int cr = t >> 4, rb = (t & 15) * 4;
  #pragma unroll
  for (int i = 0; i < 4; i++) {
    int c = cr + i * 16;
    half4v o = { ts[rb + 0][c], ts[rb + 1][c], ts[rb + 2][c], ts[rb + 3][c] };
    *(half4v*)&d[(size_t)(c0 + c) * R + r0 + rb] = o;
  }
}

// ---------------- router (+ fused fp32->fp16 cast of x) ----------------
#define RT_TOK 16
__global__ void k_router(const float* __restrict__ x, const float* __restrict__ gw,
                         _Float16* __restrict__ xb,
                         int* __restrict__ counts, int* __restrict__ perm,
                         float* __restrict__ pgate, int T) {
  __shared__ float xs[RT_TOK][520];
  __shared__ float gwt[8][520];
  __shared__ float lg[RT_TOK][8];
  int t = threadIdx.x;                 // 128 threads
  int tk0 = blockIdx.x * RT_TOK;
  for (int i = t; i < DIM * NE; i += 128) {
    int k = i >> 3, e = i & 7;
    gwt[e][k] = gw[i];
  }
  for (int i = t; i < RT_TOK * (DIM / 4); i += 128) {
    int row = i >> 7; int c4 = i & 127;       // DIM/4 == 128
    float4 v = *(const float4*)&x[(size_t)(tk0 + row) * DIM + c4 * 4];
    xs[row][c4 * 4 + 0] = v.x; xs[row][c4 * 4 + 1] = v.y;
    xs[row][c4 * 4 + 2] = v.z; xs[row][c4 * 4 + 3] = v.w;
    half4v h = { (_Float16)v.x, (_Float16)v.y, (_Float16)v.z, (_Float16)v.w };
    *(half4v*)&xb[(size_t)(tk0 + row) * DIM + c4 * 4] = h;
  }
  __syncthreads();
  int tok = t >> 3, e = t & 7;
  float acc = 0.f;
  for (int k = 0; k < DIM; k += 4) {
    float4 xv = *(const float4*)&xs[tok][k];
    float4 wv = *(const float4*)&gwt[e][k];
    acc += xv.x * wv.x + xv.y * wv.y + xv.z * wv.z + xv.w * wv.w;
  }
  lg[tok][e] = acc;
  __syncthreads();
  if (t < RT_TOK) {
    float v0 = -1e30f, v1 = -1e30f; int i0 = 0, i1 = 0;
    #pragma unroll
    for (int j = 0; j < 8; j++) { float v = lg[t][j]; if (v > v0) { v0 = v; i0 = j; } }
    #pragma unroll
    for (int j = 0; j < 8; j++) { if (j == i0) continue; float v = lg[t][j]; if (v > v1) { v1 = v; i1 = j; } }
    float g0 = 1.f / (1.f + __expf(v1 - v0));
    float g1 = 1.f - g0;
    int token = tk0 + t;
    int p0 = atomicAdd(&counts[i0], 1);
    perm[i0 * T + p0] = token; pgate[i0 * T + p0] = g0;
    int p1 = atomicAdd(&counts[i1], 1);
    perm[i1 * T + p1] = token; pgate[i1 * T + p1] = g1;
  }
}

// ---------------- MFMA GEMM: 256x256 tile, BK=64, 8 waves, flat padded grid ----
// Double-buffered (128KB dynamic LDS), depth-1 counted prefetch, row-XOR swizzle.
// Grid.x is a FLAT list over padded 256-row segments (experts 0..7 [+ master]),
// XCD-swizzled (bijective, GX % 8 == 0). Every launched block does work.
// MODE 0: fc1 (experts+master) -> gelu -> hbuf[segbase+pos] (fp16).
// MODE 1: master fc2 -> plain store to out (writes every element).
// MODE 2: expert fc2 -> gated atomicAdd into out (runs after MODE 1).

template<int K, int MODE>
__global__ __launch_bounds__(512, 1) void k_gemm(
    const _Float16* __restrict__ A,    // rows of length K (MODE0: xb, MODE1/2: hbuf)
    const _Float16* __restrict__ Bt,   // [9][N][K] fp16 (pre-transposed, slot 8 = master)
    const float* __restrict__ ebias,   // expert bias [8][N]
    const float* __restrict__ mbias,   // master bias [N]
    const int* __restrict__ counts,    // [8]
    const int* __restrict__ perm,      // [8][T]
    const float* __restrict__ pgate,   // [8][T]
    _Float16* __restrict__ hout,       // MODE0 dest [3T+pad, HID]
    float* __restrict__ out,           // MODE1/2 dest [T, DIM]
    int T, int gxd8) {
  constexpr int N = (MODE == 0) ? HID : DIM;
  constexpr int KT = K / 64;
  extern __shared__ char S[];          // 131072 bytes: 2 x (A 32KB + B 32KB)

  // ---- flat padded segment decode (+ XCD swizzle) ----
  int bxi = blockIdx.x;
  bxi = (bxi & 7) * gxd8 + (bxi >> 3);           // bijective (GX = 8*gxd8)
  int bx = bxi * 256;
  int e = 8, segbase = 0, count;
  if (MODE == 1) {
    #pragma unroll
    for (int i = 0; i < 8; i++) segbase += (counts[i] + 255) & ~255;
    count = T;
  } else {
    #pragma unroll
    for (int i = 0; i < 8; i++) {
      int seglen = (counts[i] + 255) & ~255;
      if (e == 8 && bx < segbase + seglen) { e = i; break; }
      segbase += seglen;
    }
    if (e == 8) {                                 // past expert segments
      if (MODE == 2) return;                      // experts only
      count = T;                                  // MODE0 master segment
      if (bx - segbase >= T) return;
    } else {
      count = counts[e];
    }
  }
  bool isM = (e == 8);
  int m0 = (MODE == 1) ? bx : bx - segbase;       // local row within segment
  if (MODE == 1 && m0 >= T) return;
  int n0 = blockIdx.y * 256;
  const _Float16* Be = Bt + (size_t)(MODE == 1 ? 8 : e) * N * K;
  const float* be;
  if (MODE == 0) be = isM ? mbias : ebias + (size_t)e * N;
  else if (MODE == 1) be = mbias;
  else be = ebias + (size_t)e * N;

  int t = threadIdx.x;                 // 512 threads, 8 waves (2M x 4N)
  int lane = t & 63;
  int wid = t >> 6;
  int wm = (wid >> 2) * 128;
  int wn = (wid & 3) * 64;

  // ---- staging sources (linear LDS dest; inverse-swizzled global chunk) ----
  int srow = t >> 3;
  int schunk = (t & 7) ^ (srow & 7);
  const char *aP0, *aP1, *aP2, *aP3, *bP0, *bP1, *bP2, *bP3;
  {
    int r0 = srow, r1 = 64 + srow, r2 = 128 + srow, r3 = 192 + srow;
    int p0 = m0 + r0; p0 = p0 < count ? p0 : count - 1;
    int p1 = m0 + r1; p1 = p1 < count ? p1 : count - 1;
    int p2 = m0 + r2; p2 = p2 < count ? p2 : count - 1;
    int p3 = m0 + r3; p3 = p3 < count ? p3 : count - 1;
    int a0, a1, a2, a3;
    if (MODE == 0) {
      a0 = isM ? p0 : perm[e * T + p0];
      a1 = isM ? p1 : perm[e * T + p1];
      a2 = isM ? p2 : perm[e * T + p2];
      a3 = isM ? p3 : perm[e * T + p3];
    } else {
      a0 = segbase + p0; a1 = segbase + p1; a2 = segbase + p2; a3 = segbase + p3;
    }
    aP0 = (const char*)(A + (size_t)a0 * K) + schunk * 16;
    aP1 = (const char*)(A + (size_t)a1 * K) + schunk * 16;
    aP2 = (const char*)(A + (size_t)a2 * K) + schunk * 16;
    aP3 = (const char*)(A + (size_t)a3 * K) + schunk * 16;
    bP0 = (const char*)(Be + (size_t)(n0 + r0) * K) + schunk * 16;
    bP1 = (const char*)(Be + (size_t)(n0 + r1) * K) + schunk * 16;
    bP2 = (const char*)(Be + (size_t)(n0 + r2) * K) + schunk * 16;
    bP3 = (const char*)(Be + (size_t)(n0 + r3) * K) + schunk * 16;
  }

  // ---- read-side swizzled byte offsets ----
  int l15 = lane & 15, l4 = lane >> 4, l7 = lane & 7;
  int roff0 = l15 * 128 + ((l4 ^ l7) << 4);
  int roff1 = l15 * 128 + (((4 + l4) ^ l7) << 4);

  f32x4 acc[8][4] = {};

  char* buf0 = S;
  char* buf1 = S + 65536;

#define STAGE(base, ktile) do { \
    const int off_ = (ktile) * 128; \
    gload16(aP0 + off_, (base) + t * 16); \
    gload16(aP1 + off_, (base) + 8192 + t * 16); \
    gload16(aP2 + off_, (base) + 16384 + t * 16); \
    gload16(aP3 + off_, (base) + 24576 + t * 16); \
    gload16(bP0 + off_, (base) + 32768 + t * 16); \
    gload16(bP1 + off_, (base) + 40960 + t * 16); \
    gload16(bP2 + off_, (base) + 49152 + t * 16); \
    gload16(bP3 + off_, (base) + 57344 + t * 16); \
  } while (0)

  STAGE(buf0, 0);
  for (int kt = 0; kt < KT; ++kt) {
    __builtin_amdgcn_s_barrier();
    if (kt + 1 < KT) {
      STAGE((kt & 1) ? buf0 : buf1, kt + 1);
      asm volatile("s_waitcnt vmcnt(8)" ::: "memory");
    } else {
      asm volatile("s_waitcnt vmcnt(0)" ::: "memory");
    }
    __builtin_amdgcn_sched_barrier(0);
    __builtin_amdgcn_s_barrier();
    const char* base = (kt & 1) ? buf1 : buf0;
    const char* ab = base;
    const char* bb = base + 32768;
    __builtin_amdgcn_s_setprio(1);
    #pragma unroll
    for (int kk = 0; kk < 2; ++kk) {
      int ro = kk ? roff1 : roff0;
      half8v af[8], bf[4];
      #pragma unroll
      for (int mi = 0; mi < 8; mi++)
        af[mi] = *(const half8v*)(ab + (wm + mi * 16) * 128 + ro);
      #pragma unroll
      for (int ni = 0; ni < 4; ni++)
        bf[ni] = *(const half8v*)(bb + (wn + ni * 16) * 128 + ro);
      #pragma unroll
      for (int mi = 0; mi < 8; mi++)
        #pragma unroll
        for (int ni = 0; ni < 4; ni++)
          acc[mi][ni] = __builtin_amdgcn_mfma_f32_16x16x32_f16(af[mi], bf[ni], acc[mi][ni], 0, 0, 0);
    }
    __builtin_amdgcn_s_setprio(0);
  }
#undef STAGE

  // ---- epilogue ----
  int cl = l15, rh = l4 * 4;
  float bv[4];
  #pragma unroll
  for (int ni = 0; ni < 4; ni++) bv[ni] = be[n0 + wn + ni * 16 + cl];
  #pragma unroll
  for (int mi = 0; mi < 8; mi++) {
    #pragma unroll
    for (int r = 0; r < 4; r++) {
      int pos = m0 + wm + mi * 16 + rh + r;
      if (pos >= count) continue;
      int orow; float g = 1.f;
      if (MODE == 0) orow = segbase + pos;
      else if (MODE == 1) orow = pos;
      else {
        orow = perm[e * T + pos];
        g = pgate[e * T + pos];
      }
      #pragma unroll
      for (int ni = 0; ni < 4; ni++) {
        float v = acc[mi][ni][r] + bv[ni];
        int col = n0 + wn + ni * 16 + cl;
        if (MODE == 0) {
          // jax.nn.gelu approximate=True
          float ge = v / (1.f + __expf(-1.5957691216057308f * (v + 0.044715f * v * v * v)));
          hout[(size_t)orow * HID + col] = (_Float16)ge;
        } else if (MODE == 1) {
          out[(size_t)orow * DIM + col] = v;
        } else {
          unsafeAtomicAdd(&out[(size_t)orow * DIM + col], g * v);
        }
      }
    }
  }
}

extern "C" void kernel_launch(void* const* d_in, const int* in_sizes, int n_in,
                              void* d_out, int out_size, void* d_ws, size_t ws_size,
                              hipStream_t stream) {
  const float* x         = (const float*)d_in[0];
  const float* gate_w    = (const float*)d_in[1];
  const float* master_w1 = (const float*)d_in[2];
  const float* master_b1 = (const float*)d_in[3];
  const float* master_w2 = (const float*)d_in[4];
  const float* master_b2 = (const float*)d_in[5];
  const float* expert_w1 = (const float*)d_in[6];
  const float* expert_b1 = (const float*)d_in[7];
  const float* expert_w2 = (const float*)d_in[8];
  const float* expert_b2 = (const float*)d_in[9];
  float* out = (float*)d_out;
  int T = in_sizes[0] / DIM;   // 16384 tokens

  // ---- workspace layout (~265 MB) ----
  char* p = (char*)d_ws;
  _Float16* xb   = (_Float16*)p; p += (size_t)T * DIM * 2;
  _Float16* wb1t = (_Float16*)p; p += (size_t)9 * HID * DIM * 2;  // [e][HID][DIM], master=8
  _Float16* wb2t = (_Float16*)p; p += (size_t)9 * DIM * HID * 2;  // [e][DIM][HID], master=8
  int*   counts  = (int*)p;      p += 256;
  int*   perm    = (int*)p;      p += (size_t)8 * T * 4;
  float* pgate   = (float*)p;    p += (size_t)8 * T * 4;
  _Float16* hbuf = (_Float16*)p; p += (size_t)(3 * T + 2048) * HID * 2;  // padded segments + master

  (void)hipFuncSetAttribute((const void*)&k_gemm<DIM, 0>,
                            hipFuncAttributeMaxDynamicSharedMemorySize, 131072);
  (void)hipFuncSetAttribute((const void*)&k_gemm<HID, 1>,
                            hipFuncAttributeMaxDynamicSharedMemorySize, 131072);
  (void)hipFuncSetAttribute((const void*)&k_gemm<HID, 2>,
                            hipFuncAttributeMaxDynamicSharedMemorySize, 131072);

  hipMemsetAsync(counts, 0, 64, stream);

  k_router<<<T / RT_TOK, 128, 0, stream>>>(x, gate_w, xb, counts, perm, pgate, T);

  k_transpose_cast9<<<dim3(HID / 64, DIM / 64, 9), 256, 0, stream>>>(
      expert_w1, master_w1, wb1t, DIM, HID);
  k_transpose_cast9<<<dim3(DIM / 64, HID / 64, 9), 256, 0, stream>>>(
      expert_w2, master_w2, wb2t, HID, DIM);

  // fc1 (experts + master), flat padded grid: GX = 3T/256 + 8 = 200
  int gx1 = 3 * T / 256 + 8;
  k_gemm<DIM, 0><<<dim3(gx1, HID / 256, 1), 512, 131072, stream>>>(
      xb, wb1t, expert_b1, master_b1, counts, perm, nullptr,
      hbuf, nullptr, T, gx1 / 8);

  // master fc2: plain store (writes every out element)
  int gxm = T / 256;
  k_gemm<HID, 1><<<dim3(gxm, DIM / 256, 1), 512, 131072, stream>>>(
      hbuf, wb2t, expert_b2, master_b2, counts, perm, nullptr,
      nullptr, out, T, gxm / 8);

  // expert fc2: gated atomicAdd (stream-ordered after master store)
  int gxe = 2 * T / 256 + 8;
  k_gemm<HID, 2><<<dim3(gxe, DIM / 256, 1), 512, 131072, stream>>>(
      hbuf, wb2t, expert_b2, master_b2, counts, perm, pgate,
      nullptr, out, T, gxe / 8);
}